// Round 1
// baseline (1877.425 us; speedup 1.0000x reference)
//
#include <hip/hip_runtime.h>

typedef unsigned short u16;
typedef unsigned int u32;

#define BSZ 2048
#define PAR 66048

using f32x4 = __attribute__((ext_vector_type(4))) float;
using s16x8 = __attribute__((ext_vector_type(8))) short;

__device__ __forceinline__ float sigm(float x){ return 1.f/(1.f+__expf(-x)); }
// RTNE float->bf16 (inputs finite)
__device__ __forceinline__ u16 f2bf(float f){
  u32 u = __float_as_uint(f);
  u32 r = (u + 0x7fffu + ((u >> 16) & 1u)) >> 16;
  return (u16)r;
}
__device__ __forceinline__ float bf2f(u16 u){ return __uint_as_float(((u32)u) << 16); }

// ---------------- A1: conditioning path + dense_in -> x[2048,256] (fp32) ----------------
__global__ void kA1(const float* __restrict__ act, const float* __restrict__ obs,
                    const float* __restrict__ Wci, const float* __restrict__ vci,
                    const float* __restrict__ gci, const float* __restrict__ bci,
                    const float* __restrict__ Wcl, const float* __restrict__ bcl,
                    const float* __restrict__ Win, const float* __restrict__ vin,
                    const float* __restrict__ gin, const float* __restrict__ bin,
                    float* __restrict__ x)
{
  int w = threadIdx.x >> 6, lane = threadIdx.x & 63;
  int r = blockIdx.x * 4 + w;
  // t1[ch=lane] = actions @ W_cond_in
  float av = (lane < 16) ? act[r*16 + lane] : 0.f;
  float t1 = 0.f;
  #pragma unroll
  for (int k = 0; k < 16; ++k) {
    float a = __shfl(av, k, 64);
    t1 = fmaf(a, Wci[k*64 + lane], t1);
  }
  // EvoNorm-S0, groups of 8 channels = 8 consecutive lanes
  float s1 = t1;
  s1 += __shfl_xor(s1,1,64); s1 += __shfl_xor(s1,2,64); s1 += __shfl_xor(s1,4,64);
  float mu = s1 * 0.125f;
  float d = t1 - mu; float s2 = d*d;
  s2 += __shfl_xor(s2,1,64); s2 += __shfl_xor(s2,2,64); s2 += __shfl_xor(s2,4,64);
  float rstd = rsqrtf(s2*0.125f + 1e-5f);
  float e = t1 * sigm(vci[lane]*t1) * rstd * gci[lane] + bci[lane];
  // a2 = e @ W_cond_lat + b_cl + obs_row
  float a2 = bcl[lane] + obs[r*64 + lane];
  for (int k = 0; k < 64; ++k) {
    float ek = __shfl(e, k, 64);
    a2 = fmaf(ek, Wcl[k*64 + lane], a2);
  }
  // t3 = a2 @ W_in  (4 channels per lane: ch = 4*lane+j)
  float t3[4] = {0.f,0.f,0.f,0.f};
  for (int k = 0; k < 64; ++k) {
    float ak = __shfl(a2, k, 64);
    float4 wv = *reinterpret_cast<const float4*>(&Win[k*256 + lane*4]);
    t3[0] = fmaf(ak, wv.x, t3[0]); t3[1] = fmaf(ak, wv.y, t3[1]);
    t3[2] = fmaf(ak, wv.z, t3[2]); t3[3] = fmaf(ak, wv.w, t3[3]);
  }
  // EvoNorm groups of 8 channels = lane pair (lane^1), 4 local
  float ls = t3[0]+t3[1]+t3[2]+t3[3];
  ls += __shfl_xor(ls,1,64);
  float mu2 = ls * 0.125f;
  float vs = 0.f;
  #pragma unroll
  for (int j = 0; j < 4; ++j){ float dd = t3[j]-mu2; vs += dd*dd; }
  vs += __shfl_xor(vs,1,64);
  float rs2 = rsqrtf(vs*0.125f + 1e-5f);
  float xo[4];
  #pragma unroll
  for (int j = 0; j < 4; ++j){
    int ch = lane*4 + j;
    xo[j] = t3[j]*sigm(vin[ch]*t3[j])*rs2*gin[ch] + bin[ch];
  }
  float4 o; o.x=xo[0]; o.y=xo[1]; o.z=xo[2]; o.w=xo[3];
  *reinterpret_cast<float4*>(&x[r*256 + lane*4]) = o;
}

// ---------------- A2: u = x @ Wk  [2048,1024] fp32 ----------------
__global__ void kA2(const float* __restrict__ x, const float* __restrict__ Wk,
                    float* __restrict__ u)
{
  __shared__ float xs[8*256];
  int tid = threadIdx.x;
  int r0 = blockIdx.x * 8;
  #pragma unroll
  for (int rr = 0; rr < 8; ++rr) xs[rr*256 + tid] = x[(r0+rr)*256 + tid];
  __syncthreads();
  float acc[8][4];
  #pragma unroll
  for (int rr = 0; rr < 8; ++rr)
    #pragma unroll
    for (int j = 0; j < 4; ++j) acc[rr][j] = 0.f;
  for (int k = 0; k < 256; ++k) {
    float4 wv = *reinterpret_cast<const float4*>(&Wk[k*1024 + tid*4]);
    #pragma unroll
    for (int rr = 0; rr < 8; ++rr){
      float xv = xs[rr*256 + k];
      acc[rr][0]=fmaf(xv,wv.x,acc[rr][0]); acc[rr][1]=fmaf(xv,wv.y,acc[rr][1]);
      acc[rr][2]=fmaf(xv,wv.z,acc[rr][2]); acc[rr][3]=fmaf(xv,wv.w,acc[rr][3]);
    }
  }
  #pragma unroll
  for (int rr = 0; rr < 8; ++rr){
    float4 o; o.x=acc[rr][0]; o.y=acc[rr][1]; o.z=acc[rr][2]; o.w=acc[rr][3];
    *reinterpret_cast<float4*>(&u[(r0+rr)*1024 + tid*4]) = o;
  }
}

// ---------------- B: chunked-parallel LSTM ----------------
// 16 WGs x 16 chunks-in-M x (W=80 warmup + L=8 real) lockstep steps.
#define LCH 8
#define WARM 80
#define STEPS (WARM + LCH)

__global__ __launch_bounds__(1024) void kB(
    const float* __restrict__ u, const float* __restrict__ Wr,
    const float* __restrict__ vl, const float* __restrict__ glp,
    const float* __restrict__ blp, u16* __restrict__ H)
{
  __shared__ __align__(16) u16 hl[16*264];   // 16 chunks x 256 bf16, row stride 264 (528B)
  int tid = threadIdx.x;
  int w = tid >> 6, lane = tid & 63;
  int q = lane >> 4, l15 = lane & 15;
  int wg = blockIdx.x;
  int ch = w*16 + l15;                       // this lane's channel (0..255)

  // Wr fragments: B[k][col], col = g*256 + ch, k = kc*32 + q*8 + j
  s16x8 wf[4][8];
  #pragma unroll
  for (int g = 0; g < 4; ++g)
    #pragma unroll
    for (int kc = 0; kc < 8; ++kc) {
      s16x8 t;
      #pragma unroll
      for (int j = 0; j < 8; ++j) {
        int k = kc*32 + q*8 + j;
        t[j] = (short)f2bf(Wr[k*1024 + g*256 + ch]);
      }
      wf[g][kc] = t;
    }
  float vlv = vl[ch], glv = glp[ch], blv = blp[ch];
  for (int i = tid; i < 16*264; i += 1024) hl[i] = 0;
  float cst[4] = {0.f,0.f,0.f,0.f};
  int tb[4];
  #pragma unroll
  for (int reg = 0; reg < 4; ++reg) tb[reg] = (wg*16 + q*4 + reg)*LCH - WARM;
  __syncthreads();

  for (int s = 0; s < STEPS; ++s) {
    // prefetch u[t][gate,ch] for the 4 chunks this lane owns in C-rows
    float uv[4][4];
    #pragma unroll
    for (int reg = 0; reg < 4; ++reg) {
      int t = tb[reg] + s; int tc = t < 0 ? 0 : t;
      const float* up = u + tc*1024 + ch;
      #pragma unroll
      for (int g = 0; g < 4; ++g) uv[reg][g] = up[g*256];
    }
    // A fragments: A[m=chunk=l15][k]
    s16x8 af[8];
    #pragma unroll
    for (int kc = 0; kc < 8; ++kc)
      af[kc] = *reinterpret_cast<const s16x8*>(&hl[l15*264 + kc*32 + q*8]);
    // z = h @ Wr  (M=16 chunks at once)
    f32x4 zacc[4];
    f32x4 zv = {0.f,0.f,0.f,0.f};
    #pragma unroll
    for (int g = 0; g < 4; ++g) zacc[g] = zv;
    #pragma unroll
    for (int kc = 0; kc < 8; ++kc)
      #pragma unroll
      for (int g = 0; g < 4; ++g)
        zacc[g] = __builtin_amdgcn_mfma_f32_16x16x32_bf16(af[kc], wf[g][kc], zacc[g], 0, 0, 0);
    // gates: C-row m = q*4+reg, col = ch
    u16 hb[4];
    #pragma unroll
    for (int reg = 0; reg < 4; ++reg) {
      float zi = zacc[0][reg] + uv[reg][0];
      float zf = zacc[1][reg] + uv[reg][1];
      float zc = zacc[2][reg] + uv[reg][2];
      float zo = zacc[3][reg] + uv[reg][3];
      // EvoNorm(cc): group of 8 channels = 8 lanes (same q)
      float s1 = zc;
      s1 += __shfl_xor(s1,1,64); s1 += __shfl_xor(s1,2,64); s1 += __shfl_xor(s1,4,64);
      float mu = s1 * 0.125f;
      float d = zc - mu; float s2 = d*d;
      s2 += __shfl_xor(s2,1,64); s2 += __shfl_xor(s2,2,64); s2 += __shfl_xor(s2,4,64);
      float rstd = rsqrtf(s2*0.125f + 1e-5f);
      float encc = zc * sigm(vlv*zc) * rstd * glv + blv;
      float cn = sigm(zf)*cst[reg] + sigm(zi)*encc;
      // EvoNorm(c_new)
      float s3 = cn;
      s3 += __shfl_xor(s3,1,64); s3 += __shfl_xor(s3,2,64); s3 += __shfl_xor(s3,4,64);
      float mu2 = s3 * 0.125f;
      float d2 = cn - mu2; float s4 = d2*d2;
      s4 += __shfl_xor(s4,1,64); s4 += __shfl_xor(s4,2,64); s4 += __shfl_xor(s4,4,64);
      float rstd2 = rsqrtf(s4*0.125f + 1e-5f);
      float hn = sigm(zo) * (cn * sigm(vlv*cn) * rstd2 * glv + blv);
      int t = tb[reg] + s;
      if (t < 0) { cn = 0.f; hn = 0.f; }   // virtual pre-t=0 steps: state stays zero (exact)
      cst[reg] = cn;
      hb[reg] = f2bf(hn);
      if (s >= WARM) H[t*256 + ch] = hb[reg];
    }
    __syncthreads();                       // all A-reads done before overwriting h
    #pragma unroll
    for (int reg = 0; reg < 4; ++reg)
      hl[(q*4+reg)*264 + ch] = hb[reg];
    __syncthreads();                       // h visible for next step
  }
}

// ---------------- C0: pack W_out fp32 -> bf16 MFMA-B-fragment layout ----------------
__global__ void kC0(const float* __restrict__ Wo, u16* __restrict__ Wb)
{
  int id = blockIdx.x*256 + threadIdx.x;   // nt*512 + kc*64 + lane
  int lane = id & 63;
  int kc = (id >> 6) & 7;
  int nt = id >> 9;
  int q = lane >> 4, l15 = lane & 15;
  int col = nt*16 + l15;
  s16x8 t;
  #pragma unroll
  for (int j = 0; j < 8; ++j) {
    int k = kc*32 + q*8 + j;
    t[j] = (short)f2bf(Wo[k*PAR + col]);
  }
  *reinterpret_cast<s16x8*>(&Wb[(size_t)id*8]) = t;
}

// ---------------- C1: x2 = EvoNorm32(H @ W_d0) -> bf16 [2048,256] ----------------
__global__ void kC1(const u16* __restrict__ H, const float* __restrict__ Wd0,
                    const float* __restrict__ vd, const float* __restrict__ gd,
                    const float* __restrict__ bd, u16* __restrict__ x2)
{
  __shared__ float hs[8*256];
  int tid = threadIdx.x;
  int r0 = blockIdx.x * 8;
  #pragma unroll
  for (int rr = 0; rr < 8; ++rr) hs[rr*256 + tid] = bf2f(H[(r0+rr)*256 + tid]);
  __syncthreads();
  float acc[8];
  #pragma unroll
  for (int rr = 0; rr < 8; ++rr) acc[rr] = 0.f;
  for (int k = 0; k < 256; ++k) {
    float wv = Wd0[k*256 + tid];
    #pragma unroll
    for (int rr = 0; rr < 8; ++rr) acc[rr] = fmaf(hs[rr*256 + k], wv, acc[rr]);
  }
  float vdv = vd[tid], gdv = gd[tid], bdv = bd[tid];
  #pragma unroll
  for (int rr = 0; rr < 8; ++rr){
    float xv = acc[rr];
    float s1 = xv;
    s1 += __shfl_xor(s1,1,64); s1 += __shfl_xor(s1,2,64); s1 += __shfl_xor(s1,4,64);
    float mu = s1 * 0.125f;
    float d = xv - mu; float s2 = d*d;
    s2 += __shfl_xor(s2,1,64); s2 += __shfl_xor(s2,2,64); s2 += __shfl_xor(s2,4,64);
    float rstd = rsqrtf(s2*0.125f + 1e-5f);
    x2[(r0+rr)*256 + tid] = f2bf(xv*sigm(vdv*xv)*rstd*gdv + bdv);
  }
}

// ---------------- C2: out = x2 @ W_out + b_out  [2048,66048] fp32 ----------------
__global__ __launch_bounds__(256) void kC2(
    const u16* __restrict__ x2, const u16* __restrict__ Wb,
    const float* __restrict__ bo, float* __restrict__ out)
{
  __shared__ __align__(16) u16 bs[16384];   // 4 ntiles x 8 kc x 64 lanes x 8 bf16 = 32KB
  int tid = threadIdx.x;
  int w = tid >> 6, lane = tid & 63, q = lane >> 4, l15 = lane & 15;
  int Nblk = blockIdx.x % 1032;
  int Mb = (blockIdx.x / 1032) * 256;
  const u16* src = Wb + (size_t)Nblk*16384;
  #pragma unroll
  for (int i = 0; i < 8; ++i) {
    int idx = (i*256 + tid)*8;
    *reinterpret_cast<s16x8*>(&bs[idx]) = *reinterpret_cast<const s16x8*>(&src[idx]);
  }
  __syncthreads();
  f32x4 acc[4][4];
  f32x4 zv = {0.f,0.f,0.f,0.f};
  #pragma unroll
  for (int mt = 0; mt < 4; ++mt)
    #pragma unroll
    for (int nt = 0; nt < 4; ++nt) acc[mt][nt] = zv;
  int rowbase = Mb + w*64;                  // each wave owns 64 M-rows
  #pragma unroll
  for (int kc = 0; kc < 8; ++kc) {
    s16x8 a[4];
    #pragma unroll
    for (int mt = 0; mt < 4; ++mt)
      a[mt] = *reinterpret_cast<const s16x8*>(&x2[(rowbase + mt*16 + l15)*256 + kc*32 + q*8]);
    #pragma unroll
    for (int nt = 0; nt < 4; ++nt) {
      s16x8 b = *reinterpret_cast<const s16x8*>(&bs[((nt*8 + kc)*64 + lane)*8]);
      #pragma unroll
      for (int mt = 0; mt < 4; ++mt)
        acc[mt][nt] = __builtin_amdgcn_mfma_f32_16x16x32_bf16(a[mt], b, acc[mt][nt], 0, 0, 0);
    }
  }
  #pragma unroll
  for (int nt = 0; nt < 4; ++nt){
    int n = Nblk*64 + nt*16 + l15;
    float bv = bo[n];
    #pragma unroll
    for (int mt = 0; mt < 4; ++mt)
      #pragma unroll
      for (int reg = 0; reg < 4; ++reg){
        int row = rowbase + mt*16 + q*4 + reg;
        out[(size_t)row*PAR + n] = acc[mt][nt][reg] + bv;
      }
  }
}

extern "C" void kernel_launch(void* const* d_in, const int* in_sizes, int n_in,
                              void* d_out, int out_size, void* d_ws, size_t ws_size,
                              hipStream_t stream)
{
  const float* act = (const float*)d_in[0];
  const float* obs = (const float*)d_in[1];
  const float* Wci = (const float*)d_in[2];
  const float* vci = (const float*)d_in[3];
  const float* gci = (const float*)d_in[4];
  const float* bci = (const float*)d_in[5];
  const float* Wcl = (const float*)d_in[6];
  const float* bcl = (const float*)d_in[7];
  const float* Win = (const float*)d_in[8];
  const float* vin = (const float*)d_in[9];
  const float* gin = (const float*)d_in[10];
  const float* bin = (const float*)d_in[11];
  const float* Wk  = (const float*)d_in[12];
  const float* Wr  = (const float*)d_in[13];
  const float* vl  = (const float*)d_in[14];
  const float* gl  = (const float*)d_in[15];
  const float* bl  = (const float*)d_in[16];
  const float* Wd0 = (const float*)d_in[17];
  const float* vd0 = (const float*)d_in[18];
  const float* gd0 = (const float*)d_in[19];
  const float* bd0 = (const float*)d_in[20];
  const float* Wo  = (const float*)d_in[21];
  const float* bo  = (const float*)d_in[22];
  float* out = (float*)d_out;

  char* ws = (char*)d_ws;
  float* u   = (float*)(ws);                 // 8 MB  [2048][1024] fp32
  float* x   = (float*)(ws + (8u<<20));      // 2 MB  [2048][256]  fp32
  u16*   H   = (u16*)  (ws + (10u<<20));     // 1 MB  [2048][256]  bf16
  u16*   x2  = (u16*)  (ws + (11u<<20));     // 1 MB  [2048][256]  bf16
  u16*   Wb  = (u16*)  (ws + (12u<<20));     // 33.8 MB packed W_out bf16

  kA1<<<512, 256, 0, stream>>>(act, obs, Wci, vci, gci, bci, Wcl, bcl, Win, vin, gin, bin, x);
  kA2<<<256, 256, 0, stream>>>(x, Wk, u);
  kC0<<<8256, 256, 0, stream>>>(Wo, Wb);
  kB<<<16, 1024, 0, stream>>>(u, Wr, vl, gl, bl, H);
  kC1<<<256, 256, 0, stream>>>(H, Wd0, vd0, gd0, bd0, x2);
  kC2<<<8256, 256, 0, stream>>>(x2, Wb, bo, out);
}